// Round 8
// baseline (30.551 us; speedup 1.0000x reference)
//
#include <hip/hip_runtime.h>

namespace {

constexpr int CH    = 256;
constexpr int HH    = 256;
constexpr int WW    = 256;
constexpr int NBOX  = 100;
constexpr int MAXN  = 100;
constexpr int BLOCK = 256;
constexpr int SPLIT = 4;                  // blocks per channel
constexpr int VPC   = HH * WW / 4;        // 16384 float4 per channel
constexpr int VPB   = VPC / SPLIT;        // 4096 float4 per block
constexpr int ITER  = VPB / BLOCK;        // 16 stores per thread

typedef float f4 __attribute__((ext_vector_type(4)));

__global__ __launch_bounds__(BLOCK) void comm_kernel(
    const float* __restrict__ boxes,   // [100,8,3]
    const float* __restrict__ scores,  // [100]
    const float* __restrict__ feat,    // [256,256,256]
    float* __restrict__ out)           // [256,256,256]
{
    __shared__ float red[BLOCK / 64][4];
    __shared__ float sS[4];

    const int tid  = threadIdx.x;
    const int c    = blockIdx.x >> 2;      // SPLIT = 4
    const int part = blockIdx.x & 3;

    // ---- per-box term, fully in registers (no compaction needed):
    // S_k = sum_i p_i*term_i + (100-cnt)*term_0
    int   pc = 0;
    float T0 = 0.f, T1 = 0.f, T2 = 0.f, T3 = 0.f;   // predicate-weighted
    float U0 = 0.f, U1 = 0.f, U2 = 0.f, U3 = 0.f;   // raw (kept by tid 0)
    if (tid < NBOX) {
        bool p = scores[tid] > 0.0f;
        pc = p ? 1 : 0;

        const float* bp = boxes + tid * 24;
        float lx = bp[0], ly = bp[1];
        float rx = lx,    ry = ly;
        #pragma unroll
        for (int k = 1; k < 8; ++k) {
            float x = bp[k * 3 + 0], y = bp[k * 3 + 1];
            lx = fminf(lx, x); rx = fmaxf(rx, x);
            ly = fminf(ly, y); ry = fmaxf(ry, y);
        }
        const float inv_vox = 1.0f / 160.0f;
        float cx = ((lx + rx) * 0.5f + 128.0f) * inv_vox;
        float cy = ((ly + ry) * 0.5f + 128.0f) * inv_vox;
        float lxn = (lx + 128.0f) * inv_vox, rxn = (rx + 128.0f) * inv_vox;
        float lyn = (ly + 128.0f) * inv_vox, ryn = (ry + 128.0f) * inv_vox;
        float bev = (ryn - lyn) * (rxn - lxn);
        float a   = 1.0f / (2.0f * bev * bev);

        // grid_sample (align_corners=False, zero padding)
        float ix = ((cx + 1.0f) * (float)WW - 1.0f) * 0.5f;
        float iy = ((cy + 1.0f) * (float)HH - 1.0f) * 0.5f;
        float x0f = floorf(ix), y0f = floorf(iy);
        float wx1 = ix - x0f, wx0 = 1.0f - wx1;
        float wy1 = iy - y0f, wy0 = 1.0f - wy1;
        int x0 = (int)x0f, y0 = (int)y0f;
        int x1 = x0 + 1,  y1 = y0 + 1;
        bool vx0 = (x0 >= 0) && (x0 < WW), vx1 = (x1 >= 0) && (x1 < WW);
        bool vy0 = (y0 >= 0) && (y0 < HH), vy1 = (y1 >= 0) && (y1 < HH);
        float w00 = (vx0 && vy0) ? wx0 * wy0 : 0.0f;
        float w10 = (vx1 && vy0) ? wx1 * wy0 : 0.0f;
        float w01 = (vx0 && vy1) ? wx0 * wy1 : 0.0f;
        float w11 = (vx1 && vy1) ? wx1 * wy1 : 0.0f;
        int cx0 = min(max(x0, 0), WW - 1), cx1 = min(max(x1, 0), WW - 1);
        int cy0 = min(max(y0, 0), HH - 1), cy1 = min(max(y1, 0), HH - 1);

        const float* fc = feat + (size_t)c * (HH * WW);
        float cpf = fc[cy0 * WW + cx0] * w00
                  + fc[cy0 * WW + cx1] * w10
                  + fc[cy1 * WW + cx0] * w01
                  + fc[cy1 * WW + cx1] * w11;

        float pa = cpf * a;
        U0 = pa;
        U1 = pa * cx;
        U2 = pa * cy;
        U3 = pa * (cx * cx + cy * cy);
        if (p) { T0 = U0; T1 = U1; T2 = U2; T3 = U3; }
    }
    const int cnt = __syncthreads_count(pc);   // barrier #1 + popcount

    // ---- register shuffle-reduce within each wave ----
    #pragma unroll
    for (int off = 32; off > 0; off >>= 1) {
        T0 += __shfl_down(T0, off);
        T1 += __shfl_down(T1, off);
        T2 += __shfl_down(T2, off);
        T3 += __shfl_down(T3, off);
    }
    if ((tid & 63) == 0) {
        int wv = tid >> 6;
        red[wv][0] = T0; red[wv][1] = T1; red[wv][2] = T2; red[wv][3] = T3;
    }
    __syncthreads();                           // barrier #2
    if (tid == 0) {
        float e = (float)(MAXN - cnt);
        float t0 = e * U0, t1 = e * U1, t2 = e * U2, t3 = e * U3;
        #pragma unroll
        for (int wv = 0; wv < BLOCK / 64; ++wv) {
            t0 += red[wv][0]; t1 += red[wv][1];
            t2 += red[wv][2]; t3 += red[wv][3];
        }
        const float invN = 1.0f / (float)MAXN;
        sS[0] = t0 * invN; sS[1] = t1 * invN;
        sS[2] = t2 * invN; sS[3] = t3 * invN;
    }
    __syncthreads();                           // barrier #3

    // ---- streaming fill: out = s0*(w^2+h^2) - 2w*s1 - 2h*s2 + s3 ----
    const float s0 = sS[0], s1 = sS[1], s2 = sS[2], s3 = sS[3];

    const float wbase = (float)((tid & 63) << 2);  // column invariant per thread
    f4 wq;
    {
        float w0 = wbase, w1 = wbase + 1.0f, w2 = wbase + 2.0f, w3 = wbase + 3.0f;
        wq.x = s0 * (w0 * w0) - 2.0f * w0 * s1;
        wq.y = s0 * (w1 * w1) - 2.0f * w1 * s1;
        wq.z = s0 * (w2 * w2) - 2.0f * w2 * s1;
        wq.w = s0 * (w3 * w3) - 2.0f * w3 * s1;
    }

    f4* oc = (f4*)(out + (size_t)c * (HH * WW));
    const int beg = part * VPB;
    float hf = (float)((beg + tid) >> 6);   // row advances by 4 per iter
    #pragma unroll
    for (int it = 0; it < ITER; ++it) {
        float hterm = s0 * (hf * hf) - 2.0f * hf * s2 + s3;
        f4 v;
        v.x = wq.x + hterm;
        v.y = wq.y + hterm;
        v.z = wq.z + hterm;
        v.w = wq.w + hterm;
        oc[beg + it * BLOCK + tid] = v;
        hf += 4.0f;
    }
}

} // namespace

extern "C" void kernel_launch(void* const* d_in, const int* in_sizes, int n_in,
                              void* d_out, int out_size, void* d_ws, size_t ws_size,
                              hipStream_t stream) {
    const float* boxes  = (const float*)d_in[0];  // pred_box_infra [100,8,3]
    const float* scores = (const float*)d_in[1];  // pred_score_infra [100]
    const float* feat   = (const float*)d_in[2];  // infra_features [1,256,256,256]
    float* out = (float*)d_out;                   // [1,256,256,256] f32

    // DIAGNOSTIC: launch the identical (idempotent) kernel twice.
    // dur = F + 2K; with round-7's F + K = 18.1 us this separates fixed
    // overhead F from true kernel time K. Output is unchanged.
    comm_kernel<<<dim3(CH * SPLIT), dim3(BLOCK), 0, stream>>>(boxes, scores, feat, out);
    comm_kernel<<<dim3(CH * SPLIT), dim3(BLOCK), 0, stream>>>(boxes, scores, feat, out);
}

// Round 9
// 17.592 us; speedup vs baseline: 1.7367x; 1.7367x over previous
//
#include <hip/hip_runtime.h>

namespace {

constexpr int CH    = 256;
constexpr int HH    = 256;
constexpr int WW    = 256;
constexpr int NBOX  = 100;
constexpr int MAXN  = 100;
constexpr int BLOCK = 256;
constexpr int SPLIT = 4;                  // blocks per channel
constexpr int VPC   = HH * WW / 4;        // 16384 float4 per channel
constexpr int VPB   = VPC / SPLIT;        // 4096 float4 per block
constexpr int ITER  = VPB / BLOCK;        // 16 stores per thread

typedef float f4 __attribute__((ext_vector_type(4)));

__global__ __launch_bounds__(BLOCK) void comm_kernel(
    const float* __restrict__ boxes,   // [100,8,3]
    const float* __restrict__ scores,  // [100]
    const float* __restrict__ feat,    // [256,256,256]
    float* __restrict__ out)           // [256,256,256]
{
    __shared__ float red[BLOCK / 64][4];  // per-wave partial sums
    __shared__ float sU[4];               // raw term of box 0 (padding term)

    const int tid  = threadIdx.x;
    const int c    = blockIdx.x >> 2;      // SPLIT = 4
    const int part = blockIdx.x & 3;

    // ---- per-box term, fully in registers:
    // S_k = ( sum_i p_i*term_i + (100-cnt)*term_0 ) / 100
    int   pc = 0;
    float T0 = 0.f, T1 = 0.f, T2 = 0.f, T3 = 0.f;   // predicate-weighted
    if (tid < NBOX) {
        bool p = scores[tid] > 0.0f;
        pc = p ? 1 : 0;

        // vectorized box load: 8 points x 3 floats = 6 float4
        const f4* bp4 = (const f4*)(boxes + tid * 24);
        f4 q0 = bp4[0], q1 = bp4[1], q2 = bp4[2],
           q3 = bp4[3], q4 = bp4[4], q5 = bp4[5];
        // point k: x = flat[3k], y = flat[3k+1]
        float lx = q0.x, rx = q0.x, ly = q0.y, ry = q0.y;
#define UPD(X, Y) { lx = fminf(lx, (X)); rx = fmaxf(rx, (X)); \
                    ly = fminf(ly, (Y)); ry = fmaxf(ry, (Y)); }
        UPD(q0.w, q1.x)   // k=1
        UPD(q1.z, q1.w)   // k=2
        UPD(q2.y, q2.z)   // k=3
        UPD(q3.x, q3.y)   // k=4
        UPD(q3.w, q4.x)   // k=5
        UPD(q4.z, q4.w)   // k=6
        UPD(q5.y, q5.z)   // k=7
#undef UPD
        const float inv_vox = 1.0f / 160.0f;
        float cx = ((lx + rx) * 0.5f + 128.0f) * inv_vox;
        float cy = ((ly + ry) * 0.5f + 128.0f) * inv_vox;
        float lxn = (lx + 128.0f) * inv_vox, rxn = (rx + 128.0f) * inv_vox;
        float lyn = (ly + 128.0f) * inv_vox, ryn = (ry + 128.0f) * inv_vox;
        float bev = (ryn - lyn) * (rxn - lxn);
        float a   = 1.0f / (2.0f * bev * bev);

        // grid_sample (align_corners=False, zero padding)
        float ix = ((cx + 1.0f) * (float)WW - 1.0f) * 0.5f;
        float iy = ((cy + 1.0f) * (float)HH - 1.0f) * 0.5f;
        float x0f = floorf(ix), y0f = floorf(iy);
        float wx1 = ix - x0f, wx0 = 1.0f - wx1;
        float wy1 = iy - y0f, wy0 = 1.0f - wy1;
        int x0 = (int)x0f, y0 = (int)y0f;
        int x1 = x0 + 1,  y1 = y0 + 1;
        bool vx0 = (x0 >= 0) && (x0 < WW), vx1 = (x1 >= 0) && (x1 < WW);
        bool vy0 = (y0 >= 0) && (y0 < HH), vy1 = (y1 >= 0) && (y1 < HH);
        float w00 = (vx0 && vy0) ? wx0 * wy0 : 0.0f;
        float w10 = (vx1 && vy0) ? wx1 * wy0 : 0.0f;
        float w01 = (vx0 && vy1) ? wx0 * wy1 : 0.0f;
        float w11 = (vx1 && vy1) ? wx1 * wy1 : 0.0f;
        int cx0 = min(max(x0, 0), WW - 1), cx1 = min(max(x1, 0), WW - 1);
        int cy0 = min(max(y0, 0), HH - 1), cy1 = min(max(y1, 0), HH - 1);

        const float* fc = feat + (size_t)c * (HH * WW);
        float cpf = fc[cy0 * WW + cx0] * w00
                  + fc[cy0 * WW + cx1] * w10
                  + fc[cy1 * WW + cx0] * w01
                  + fc[cy1 * WW + cx1] * w11;

        float pa = cpf * a;
        float U0 = pa;
        float U1 = pa * cx;
        float U2 = pa * cy;
        float U3 = pa * (cx * cx + cy * cy);
        if (p) { T0 = U0; T1 = U1; T2 = U2; T3 = U3; }
        if (tid == 0) { sU[0] = U0; sU[1] = U1; sU[2] = U2; sU[3] = U3; }
    }

    // in-wave shuffle reduce (pre-barrier)
    #pragma unroll
    for (int off = 32; off > 0; off >>= 1) {
        T0 += __shfl_down(T0, off);
        T1 += __shfl_down(T1, off);
        T2 += __shfl_down(T2, off);
        T3 += __shfl_down(T3, off);
    }
    if ((tid & 63) == 0) {
        int wv = tid >> 6;
        red[wv][0] = T0; red[wv][1] = T1; red[wv][2] = T2; red[wv][3] = T3;
    }

    // the ONLY barrier: sync + predicate count in one op
    const int cnt = __syncthreads_count(pc);

    // every thread reconstructs S directly (no serial section, no 2nd barrier)
    const float e    = (float)(MAXN - cnt);
    const float invN = 1.0f / (float)MAXN;
    const float s0 = (red[0][0] + red[1][0] + red[2][0] + red[3][0] + e * sU[0]) * invN;
    const float s1 = (red[0][1] + red[1][1] + red[2][1] + red[3][1] + e * sU[1]) * invN;
    const float s2 = (red[0][2] + red[1][2] + red[2][2] + red[3][2] + e * sU[2]) * invN;
    const float s3 = (red[0][3] + red[1][3] + red[2][3] + red[3][3] + e * sU[3]) * invN;

    // ---- streaming fill: out = s0*(w^2+h^2) - 2w*s1 - 2h*s2 + s3 ----
    const float wbase = (float)((tid & 63) << 2);  // column invariant per thread
    f4 wq;
    {
        float w0 = wbase, w1 = wbase + 1.0f, w2 = wbase + 2.0f, w3 = wbase + 3.0f;
        wq.x = s0 * (w0 * w0) - 2.0f * w0 * s1;
        wq.y = s0 * (w1 * w1) - 2.0f * w1 * s1;
        wq.z = s0 * (w2 * w2) - 2.0f * w2 * s1;
        wq.w = s0 * (w3 * w3) - 2.0f * w3 * s1;
    }

    f4* oc = (f4*)(out + (size_t)c * (HH * WW));
    const int beg = part * VPB;
    float hf = (float)((beg + tid) >> 6);   // row advances by 4 per iter
    #pragma unroll
    for (int it = 0; it < ITER; ++it) {
        float hterm = s0 * (hf * hf) - 2.0f * hf * s2 + s3;
        f4 v;
        v.x = wq.x + hterm;
        v.y = wq.y + hterm;
        v.z = wq.z + hterm;
        v.w = wq.w + hterm;
        oc[beg + it * BLOCK + tid] = v;
        hf += 4.0f;
    }
}

} // namespace

extern "C" void kernel_launch(void* const* d_in, const int* in_sizes, int n_in,
                              void* d_out, int out_size, void* d_ws, size_t ws_size,
                              hipStream_t stream) {
    const float* boxes  = (const float*)d_in[0];  // pred_box_infra [100,8,3]
    const float* scores = (const float*)d_in[1];  // pred_score_infra [100]
    const float* feat   = (const float*)d_in[2];  // infra_features [1,256,256,256]
    float* out = (float*)d_out;                   // [1,256,256,256] f32
    comm_kernel<<<dim3(CH * SPLIT), dim3(BLOCK), 0, stream>>>(boxes, scores, feat, out);
}